// Round 3
// baseline (872.745 us; speedup 1.0000x reference)
//
#include <hip/hip_runtime.h>
#include <cmath>

// Problem constants
static constexpr int kB   = 16;
static constexpr int kC   = 64;
static constexpr int kH   = 160;
static constexpr int kW   = 192;
static constexpr int kN   = 1000;
static constexpr int kAFC = 16;
static constexpr int kS   = 96;
static constexpr int kNC  = 2;
static constexpr int kD   = kAFC * kH;     // 2560
static constexpr int kHW  = kH * kW;       // 30720
static constexpr int kNM1 = kN - 1;        // 999
static constexpr int kM   = kB * kN;       // 16000
static constexpr int kRP  = kNC + 3 + 3 * kS; // 293
static constexpr int kK2  = 2 * kD;        // 5120
static constexpr int kNP  = 1024;          // padded N for att GEMM

// d_out layout (floats)
static constexpr size_t OFF_RP   = 0;
static constexpr size_t OFF_ATTN = (size_t)kB * kN * kRP;
static constexpr size_t OFF_FEAT = OFF_ATTN + (size_t)kB * kN * kN;

// ws layout (bytes)
static constexpr size_t WB_BAF   = 0;                                    // bf16 [16000][2560]
static constexpr size_t WB_BAFT  = WB_BAF   + (size_t)kM * kD * 2;       // bf16 [16][2560][1024]
static constexpr size_t WB_ATTF  = WB_BAFT  + (size_t)kB * kD * kNP * 2; // bf16 [16000][2560]
static constexpr size_t WB_ATTNB = WB_ATTF  + (size_t)kM * kD * 2;       // bf16 [16][1024][1024]
static constexpr size_t WB_SCORE = WB_ATTNB + (size_t)kB * kNP * kNP * 2;// f32  [16000][999]
static constexpr size_t WB_ATTNW = WB_SCORE + (size_t)kM * kNM1 * 4;     // bf16 [1024][2560]
static constexpr size_t WB_WHEAD = WB_ATTNW + (size_t)kNP * kD * 2;      // bf16 [384][5120]
static constexpr size_t WB_FLAG  = WB_WHEAD + (size_t)384 * kK2 * 2;     // int

typedef __attribute__((ext_vector_type(8))) short bf16x8;
typedef __attribute__((ext_vector_type(4))) float f32x4;

static __device__ inline short f2bf(float f) {
  union { float f; unsigned u; } x; x.f = f;
  unsigned r = (x.u + 0x7FFFu + ((x.u >> 16) & 1u)) >> 16;
  return (short)r;
}

#define GLOAD_LDS16(gp, lp) __builtin_amdgcn_global_load_lds( \
    (const __attribute__((address_space(1))) void*)(gp),      \
    (__attribute__((address_space(3))) void*)(lp), 16, 0, 0)

// ---------------- mask dtype detection ----------------
__global__ void k_detect(const unsigned char* __restrict__ m, int* __restrict__ flag) {
  __shared__ int c1, c2, c3;
  if (threadIdx.x == 0) { c1 = 0; c2 = 0; c3 = 0; }
  __syncthreads();
  int l1 = 0, l2 = 0, l3 = 0;
  for (int g = threadIdx.x; g < (kN * kH) / 4; g += blockDim.x) {
    l1 += (m[4 * g + 1] != 0);
    l2 += (m[4 * g + 2] != 0);
    l3 += (m[4 * g + 3] != 0);
  }
  atomicAdd(&c1, l1); atomicAdd(&c2, l2); atomicAdd(&c3, l3);
  __syncthreads();
  if (threadIdx.x == 0) {
    int f;
    if (c1 > 0)            f = 1;  // uint8 bools
    else if (c2 | c3)      f = 2;  // float32 bools
    else                   f = 0;  // int32 bools
    *flag = f;
  }
}

// ---------------- 1x1 conv (fp32, feats is an output) ----------------
__global__ __launch_bounds__(256) void k_conv(const float* __restrict__ bf,
                                              const float* __restrict__ cw,
                                              const float* __restrict__ cb,
                                              float* __restrict__ feats) {
  __shared__ float w[kAFC * kC];
  __shared__ float bsh[kAFC];
  for (int i = threadIdx.x; i < kAFC * kC; i += 256) w[i] = cw[i];
  if (threadIdx.x < kAFC) bsh[threadIdx.x] = cb[threadIdx.x];
  __syncthreads();
  int idx = blockIdx.x * 256 + threadIdx.x;
  if (idx >= kB * kHW) return;
  int b = idx / kHW, p = idx % kHW;
  float acc[kAFC];
#pragma unroll
  for (int o = 0; o < kAFC; o++) acc[o] = bsh[o];
  const float* src = bf + (size_t)b * kC * kHW + p;
#pragma unroll 4
  for (int c = 0; c < kC; c++) {
    float v = src[(size_t)c * kHW];
#pragma unroll
    for (int o = 0; o < kAFC; o++) acc[o] += v * w[o * kC + c];
  }
  float* dst = feats + (size_t)b * kAFC * kHW + p;
#pragma unroll
  for (int o = 0; o < kAFC; o++) dst[(size_t)o * kHW] = acc[o];
}

// ---------------- gather rois -> baf (bf16) ----------------
__global__ __launch_bounds__(256) void k_gather(const float* __restrict__ feats,
                                                const int* __restrict__ cut,
                                                const void* __restrict__ mask,
                                                const int* __restrict__ flag,
                                                short* __restrict__ baf) {
  int idx = blockIdx.x * 256 + threadIdx.x;
  if (idx >= kB * kN * kH) return;
  int b = idx / (kN * kH);
  int r = idx % (kN * kH);
  int n = r / kH, h = r % kH;
  int f = *flag;
  bool inv;
  if (f == 0)      inv = ((const int*)mask)[r] != 0;
  else if (f == 1) inv = ((const unsigned char*)mask)[r] != 0;
  else             inv = ((const float*)mask)[r] != 0.0f;
  int x = cut[r];
  short* dst = baf + (size_t)(b * kN + n) * kD + h;
  if (inv) {
#pragma unroll
    for (int a = 0; a < kAFC; a++) dst[a * kH] = 0;
  } else {
    const float* sp = feats + (size_t)b * kAFC * kHW + (size_t)h * kW + x;
#pragma unroll
    for (int a = 0; a < kAFC; a++) dst[a * kH] = f2bf(sp[(size_t)a * kHW]);
  }
}

// ---------------- transpose baf -> bafT [b][d][n_pad] (zero-pad n>=1000) ----
__global__ __launch_bounds__(256) void k_transpose(const short* __restrict__ baf,
                                                   short* __restrict__ bafT) {
  __shared__ short t[64][66];
  int b = blockIdx.z, n0 = blockIdx.y * 64, d0 = blockIdx.x * 64;
  int c = threadIdx.x & 63, r4 = threadIdx.x >> 6;  // c: 0..63, r4: 0..3
#pragma unroll
  for (int i = 0; i < 16; i++) {
    int nl = r4 + i * 4;
    int n = n0 + nl;
    short v = (n < kN) ? baf[(size_t)(b * kN + n) * kD + d0 + c] : (short)0;
    t[nl][c] = v;
  }
  __syncthreads();
#pragma unroll
  for (int i = 0; i < 16; i++) {
    int dl = r4 + i * 4;
    bafT[((size_t)b * kD + d0 + dl) * kNP + n0 + c] = t[c][dl];
  }
}

// ---------------- convert attn_w -> bf16 [1024][2560] (pad rows) ------------
__global__ __launch_bounds__(256) void k_cvt_attnw(const float* __restrict__ w,
                                                   short* __restrict__ o) {
  int idx = blockIdx.x * 256 + threadIdx.x;
  if (idx >= kNP * kD) return;
  int j = idx / kD;
  o[idx] = (j < kNM1) ? f2bf(w[idx]) : (short)0;
}

// ---------------- build head weight bf16 [384][5120] ------------------------
__global__ __launch_bounds__(256) void k_cvt_whead(const float* __restrict__ reg_w,
                                                   const float* __restrict__ cls_w,
                                                   short* __restrict__ o) {
  int idx = blockIdx.x * 256 + threadIdx.x;
  if (idx >= 384 * kK2) return;
  int j = idx / kK2, k = idx % kK2;
  float v = 0.f;
  if (j < 3 * kS)            v = reg_w[idx];
  else if (j < 3 * kS + kNC) v = cls_w[(size_t)(j - 3 * kS) * kK2 + k];
  o[idx] = f2bf(v);
}

// ---------------- softmax: scores -> attn_mat (f32 out) + attn bf16 padded --
__global__ __launch_bounds__(256) void k_softmax(const float* __restrict__ scores,
                                                 const float* __restrict__ anchors,
                                                 float* __restrict__ attn_out,
                                                 short* __restrict__ attn_bf,
                                                 float* __restrict__ rp) {
  int m = blockIdx.x;           // 0..15999
  int b = m / kN;
  int i = m % kN;
  const float* srow = scores + (size_t)m * kNM1;
  int tid = threadIdx.x;
  __shared__ float red[4];
  float v[4];
  float mx = -INFINITY;
#pragma unroll
  for (int t = 0; t < 4; t++) {
    int j = tid + t * 256;
    v[t] = (j < kNM1) ? srow[j] : -INFINITY;
    mx = fmaxf(mx, v[t]);
  }
#pragma unroll
  for (int o = 32; o; o >>= 1) mx = fmaxf(mx, __shfl_down(mx, o));
  if ((tid & 63) == 0) red[tid >> 6] = mx;
  __syncthreads();
  mx = fmaxf(fmaxf(red[0], red[1]), fmaxf(red[2], red[3]));
  __syncthreads();
  float s = 0.f;
#pragma unroll
  for (int t = 0; t < 4; t++) {
    int j = tid + t * 256;
    v[t] = (j < kNM1) ? __expf(v[t] - mx) : 0.f;
    s += v[t];
  }
#pragma unroll
  for (int o = 32; o; o >>= 1) s += __shfl_down(s, o);
  if ((tid & 63) == 0) red[tid >> 6] = s;
  __syncthreads();
  s = red[0] + red[1] + red[2] + red[3];
  float inv = 1.0f / s;
  float* orow = attn_out + (size_t)m * kN;
  short* brow = attn_bf + ((size_t)b * kNP + i) * kNP;
#pragma unroll
  for (int t = 0; t < 4; t++) {
    int j = tid + t * 256;
    if (j < kNM1) {
      int dst = j + (j >= i);
      float p = v[t] * inv;
      orow[dst] = p;
      brow[dst] = f2bf(p);
    }
  }
  if (tid == 0) { orow[i] = 0.f; brow[i] = 0; }
  if (tid < kNP - kN) brow[kN + tid] = 0;           // pad cols 1000..1023
  if (tid < 3) rp[(size_t)m * kRP + 2 + tid] = anchors[(size_t)i * kRP + 2 + tid];
}

// ---------------- MFMA bf16 GEMM, m97 structure (128x128 tile, BK=32) -------
// MODE 0: scores = baf @ attnw^T (+attn_b), f32 out [16000][999]
// MODE 1: attf   = attn @ bafT^T, bf16 out [16][1000][2560], batched over z
template <int MODE>
__global__ __launch_bounds__(256) void k_mfma_gemm(
    const short* __restrict__ A,
    const short* __restrict__ Bt,
    const float* __restrict__ bias,
    void* __restrict__ Cout, int K, int lda, int ldb) {
  __shared__ short smem[8192];                 // As: 8 KB, Bs: 8 KB
  char* sA = (char*)smem;
  char* sB = (char*)smem + 8192;
  int tid = threadIdx.x, lane = tid & 63, wv = tid >> 6;
  int m0 = blockIdx.x * 128, n0 = blockIdx.y * 128;
  const short* Ap = A;
  const short* Bp = Bt;
  int bz = 0;
  if (MODE == 1) {
    bz = blockIdx.z;
    Ap = A + (size_t)bz * kNP * kNP;
    Bp = Bt + (size_t)bz * kD * kNP;
  }
  int wm = (wv >> 1) * 64, wn = (wv & 1) * 64;
  int sRow = lane >> 2;          // 0..15 row within 16-row chunk
  int sKo  = (lane & 3) * 8;     // k element offset
  f32x4 acc[4][4] = {};

  for (int k0 = 0; k0 < K; k0 += 32) {
    const short* ga = Ap + (size_t)(m0 + 32 * wv + sRow) * lda + k0 + sKo;
    GLOAD_LDS16(ga,            sA + wv * 2048);
    GLOAD_LDS16(ga + 16 * lda, sA + wv * 2048 + 1024);
    const short* gb = Bp + (size_t)(n0 + 32 * wv + sRow) * ldb + k0 + sKo;
    GLOAD_LDS16(gb,            sB + wv * 2048);
    GLOAD_LDS16(gb + 16 * ldb, sB + wv * 2048 + 1024);
    __syncthreads();

    bf16x8 af[4], bfg[4];
#pragma unroll
    for (int i = 0; i < 4; i++)
      af[i] = *(const bf16x8*)(sA + ((size_t)(wm + i * 16 + (lane & 15))) * 64 + (lane >> 4) * 16);
#pragma unroll
    for (int j = 0; j < 4; j++)
      bfg[j] = *(const bf16x8*)(sB + ((size_t)(wn + j * 16 + (lane & 15))) * 64 + (lane >> 4) * 16);
#pragma unroll
    for (int i = 0; i < 4; i++)
#pragma unroll
      for (int j = 0; j < 4; j++)
        acc[i][j] = __builtin_amdgcn_mfma_f32_16x16x32_bf16(af[i], bfg[j], acc[i][j], 0, 0, 0);
    __syncthreads();
  }

  // epilogue
#pragma unroll
  for (int i = 0; i < 4; i++) {
#pragma unroll
    for (int j = 0; j < 4; j++) {
#pragma unroll
      for (int r = 0; r < 4; r++) {
        int row = m0 + wm + i * 16 + (lane >> 4) * 4 + r;
        int col = n0 + wn + j * 16 + (lane & 15);
        float v = acc[i][j][r];
        if (MODE == 0) {
          if (col < kNM1)
            ((float*)Cout)[(size_t)row * kNM1 + col] = v + bias[col];
        } else {
          if (row < kN)
            ((short*)Cout)[((size_t)bz * kN + row) * kD + col] = f2bf(v);
        }
      }
    }
  }
}

// ---------------- head GEMM: BM=64, BN=384 (single col tile), BK=32 ---------
// C = [attf|baf] @ whead^T; 2-phase double-buffered; epilogue -> rp
__global__ __launch_bounds__(256) void k_gemm_head2(
    const short* __restrict__ A,   // attf [16000][2560]
    const short* __restrict__ A2,  // baf  [16000][2560]
    const short* __restrict__ Bt,  // whead [384][5120]
    const float* __restrict__ reg_b, const float* __restrict__ cls_b,
    const float* __restrict__ anchors, float* __restrict__ rp) {
  __shared__ short smem[28672];    // 2 bufs x (A 4KB + B 24KB) = 56 KB
  int tid = threadIdx.x, lane = tid & 63, wv = tid >> 6;
  int m0 = blockIdx.x * 64;
  f32x4 acc[4][6] = {};
  int sRow = lane >> 2;            // 0..15
  int sKo  = (lane & 3) * 8;       // k element offset (x8 bf16 = 16B)

  auto STAGE = [&](int k0, int buf) {
    char* bA = (char*)smem + buf * 28672;
    char* bB = bA + 4096;
    const short* Abase = A; int kk = k0;
    if (k0 >= kD) { Abase = A2; kk = k0 - kD; }
    const short* ga = Abase + (size_t)(m0 + wv * 16 + sRow) * kD + kk + sKo;
    GLOAD_LDS16(ga, bA + wv * 1024);
#pragma unroll
    for (int g = 0; g < 6; g++) {
      const short* gb = Bt + (size_t)(g * 64 + wv * 16 + sRow) * kK2 + k0 + sKo;
      GLOAD_LDS16(gb, bB + g * 4096 + wv * 1024);
    }
  };

  STAGE(0, 0);
  __syncthreads();
  constexpr int NT = kK2 / 32;     // 160
  for (int t = 0; t < NT; t++) {
    if (t + 1 < NT) STAGE((t + 1) * 32, (t + 1) & 1);
    char* bA = (char*)smem + (size_t)(t & 1) * 28672;
    char* bB = bA + 4096;
    bf16x8 af[4], bfr[6];
#pragma unroll
    for (int i = 0; i < 4; i++)
      af[i] = *(const bf16x8*)(bA + (i * 16 + (lane & 15)) * 64 + (lane >> 4) * 16);
#pragma unroll
    for (int j = 0; j < 6; j++)
      bfr[j] = *(const bf16x8*)(bB + (wv * 96 + j * 16 + (lane & 15)) * 64 + (lane >> 4) * 16);
#pragma unroll
    for (int i = 0; i < 4; i++)
#pragma unroll
      for (int j = 0; j < 6; j++)
        acc[i][j] = __builtin_amdgcn_mfma_f32_16x16x32_bf16(af[i], bfr[j], acc[i][j], 0, 0, 0);
    __syncthreads();
  }

  // epilogue -> rp
#pragma unroll
  for (int i = 0; i < 4; i++) {
#pragma unroll
    for (int j = 0; j < 6; j++) {
#pragma unroll
      for (int r = 0; r < 4; r++) {
        int row = m0 + i * 16 + (lane >> 4) * 4 + r;
        int col = wv * 96 + j * 16 + (lane & 15);
        int n = row % kN;
        float v = acc[i][j][r];
        if (col < 3 * kS) {
          float tv = v + reg_b[col];
          if (col >= 2 * kS) tv = 1.0f / (1.0f + __expf(-tv));
          rp[(size_t)row * kRP + 5 + col] = anchors[(size_t)n * kRP + 5 + col] + tv;
        } else if (col < 3 * kS + kNC) {
          rp[(size_t)row * kRP + (col - 3 * kS)] = v + cls_b[col - 3 * kS];
        }
      }
    }
  }
}

extern "C" void kernel_launch(void* const* d_in, const int* in_sizes, int n_in,
                              void* d_out, int out_size, void* d_ws, size_t ws_size,
                              hipStream_t stream) {
  const float* bf      = (const float*)d_in[0];
  const float* conv_w  = (const float*)d_in[1];
  const float* conv_b  = (const float*)d_in[2];
  const int*   cut     = (const int*)d_in[3];
  const void*  mask    = d_in[4];
  const float* anchors = (const float*)d_in[5];
  const float* attn_w  = (const float*)d_in[6];
  const float* attn_b  = (const float*)d_in[7];
  const float* cls_w   = (const float*)d_in[8];
  const float* cls_b   = (const float*)d_in[9];
  const float* reg_w   = (const float*)d_in[10];
  const float* reg_b   = (const float*)d_in[11];

  float* out    = (float*)d_out;
  float* rp     = out + OFF_RP;
  float* attn_o = out + OFF_ATTN;
  float* feats  = out + OFF_FEAT;

  char*  ws      = (char*)d_ws;
  short* baf     = (short*)(ws + WB_BAF);
  short* bafT    = (short*)(ws + WB_BAFT);
  short* attf    = (short*)(ws + WB_ATTF);
  short* attn_bf = (short*)(ws + WB_ATTNB);
  float* scores  = (float*)(ws + WB_SCORE);
  short* attnw   = (short*)(ws + WB_ATTNW);
  short* whead   = (short*)(ws + WB_WHEAD);
  int*   flag    = (int*)(ws + WB_FLAG);

  k_detect<<<1, 256, 0, stream>>>((const unsigned char*)mask, flag);
  k_conv<<<(kB * kHW) / 256, 256, 0, stream>>>(bf, conv_w, conv_b, feats);
  k_gather<<<(kB * kN * kH) / 256, 256, 0, stream>>>(feats, cut, mask, flag, baf);
  {
    dim3 g(kD / 64, 16, kB);  // d-tiles, n-tiles, batch
    k_transpose<<<g, 256, 0, stream>>>(baf, bafT);
  }
  k_cvt_attnw<<<(kNP * kD + 255) / 256, 256, 0, stream>>>(attn_w, attnw);
  k_cvt_whead<<<(384 * kK2 + 255) / 256, 256, 0, stream>>>(reg_w, cls_w, whead);
  {
    dim3 g(kM / 128, 8);      // 125 x 8 (cols padded to 1024)
    k_mfma_gemm<0><<<g, 256, 0, stream>>>(baf, attnw, attn_b, scores, kD, kD, kD);
  }
  k_softmax<<<kM, 256, 0, stream>>>(scores, anchors, attn_o, attn_bf, rp);
  {
    dim3 g(kNP / 128, kD / 128, kB);  // 8 x 20 x 16
    k_mfma_gemm<1><<<g, 256, 0, stream>>>(attn_bf, bafT, nullptr, attf, kNP, kNP, kNP);
  }
  k_gemm_head2<<<kM / 64, 256, 0, stream>>>(attf, baf, whead, reg_b, cls_b,
                                            anchors, rp);
}

// Round 4
// 790.428 us; speedup vs baseline: 1.1041x; 1.1041x over previous
//
#include <hip/hip_runtime.h>
#include <cmath>

// Problem constants
static constexpr int kB   = 16;
static constexpr int kC   = 64;
static constexpr int kH   = 160;
static constexpr int kW   = 192;
static constexpr int kN   = 1000;
static constexpr int kAFC = 16;
static constexpr int kS   = 96;
static constexpr int kNC  = 2;
static constexpr int kD   = kAFC * kH;     // 2560
static constexpr int kHW  = kH * kW;       // 30720
static constexpr int kNM1 = kN - 1;        // 999
static constexpr int kM   = kB * kN;       // 16000
static constexpr int kRP  = kNC + 3 + 3 * kS; // 293
static constexpr int kK2  = 2 * kD;        // 5120
static constexpr int kNP  = 1024;          // padded N for att GEMM
static constexpr int kKS  = 4;             // split-K factor for head GEMM

// d_out layout (floats)
static constexpr size_t OFF_RP   = 0;
static constexpr size_t OFF_ATTN = (size_t)kB * kN * kRP;
static constexpr size_t OFF_FEAT = OFF_ATTN + (size_t)kB * kN * kN;

// ws layout (bytes)
static constexpr size_t WB_BAF   = 0;                                    // bf16 [16000][2560]
static constexpr size_t WB_BAFT  = WB_BAF   + (size_t)kM * kD * 2;       // bf16 [16][2560][1024]
static constexpr size_t WB_ATTF  = WB_BAFT  + (size_t)kB * kD * kNP * 2; // bf16 [16000][2560]
static constexpr size_t WB_ATTNW = WB_ATTF  + (size_t)kM * kD * 2;       // bf16 [1024][2560]
static constexpr size_t WB_WHEAD = WB_ATTNW + (size_t)kNP * kD * 2;      // bf16 [384][5120]
static constexpr size_t WB_ATTNB = WB_WHEAD + (size_t)384 * kK2 * 2;     // bf16 [16][1024][1024]
static constexpr size_t WB_SCORE = WB_ATTNB + (size_t)kB * kNP * kNP * 2;// f32  [16000][999]
// PART overlays ATTNB+SCORE (both dead by the time head GEMM runs)
static constexpr size_t WB_PART  = WB_ATTNB;                             // f32 [4][16000][384]
static constexpr size_t WB_FLAG  = WB_PART + (size_t)kKS * kM * 384 * 4; // int

typedef __attribute__((ext_vector_type(8))) short bf16x8;
typedef __attribute__((ext_vector_type(4))) float f32x4;

static __device__ inline short f2bf(float f) {
  union { float f; unsigned u; } x; x.f = f;
  unsigned r = (x.u + 0x7FFFu + ((x.u >> 16) & 1u)) >> 16;
  return (short)r;
}

#define GLOAD_LDS16(gp, lp) __builtin_amdgcn_global_load_lds( \
    (const __attribute__((address_space(1))) void*)(gp),      \
    (__attribute__((address_space(3))) void*)(lp), 16, 0, 0)

// ---------------- mask dtype detection ----------------
__global__ void k_detect(const unsigned char* __restrict__ m, int* __restrict__ flag) {
  __shared__ int c1, c2, c3;
  if (threadIdx.x == 0) { c1 = 0; c2 = 0; c3 = 0; }
  __syncthreads();
  int l1 = 0, l2 = 0, l3 = 0;
  for (int g = threadIdx.x; g < (kN * kH) / 4; g += blockDim.x) {
    l1 += (m[4 * g + 1] != 0);
    l2 += (m[4 * g + 2] != 0);
    l3 += (m[4 * g + 3] != 0);
  }
  atomicAdd(&c1, l1); atomicAdd(&c2, l2); atomicAdd(&c3, l3);
  __syncthreads();
  if (threadIdx.x == 0) {
    int f;
    if (c1 > 0)            f = 1;  // uint8 bools
    else if (c2 | c3)      f = 2;  // float32 bools
    else                   f = 0;  // int32 bools
    *flag = f;
  }
}

// ---------------- 1x1 conv (fp32, feats is an output) ----------------
__global__ __launch_bounds__(256) void k_conv(const float* __restrict__ bf,
                                              const float* __restrict__ cw,
                                              const float* __restrict__ cb,
                                              float* __restrict__ feats) {
  __shared__ float w[kAFC * kC];
  __shared__ float bsh[kAFC];
  for (int i = threadIdx.x; i < kAFC * kC; i += 256) w[i] = cw[i];
  if (threadIdx.x < kAFC) bsh[threadIdx.x] = cb[threadIdx.x];
  __syncthreads();
  int idx = blockIdx.x * 256 + threadIdx.x;
  if (idx >= kB * kHW) return;
  int b = idx / kHW, p = idx % kHW;
  float acc[kAFC];
#pragma unroll
  for (int o = 0; o < kAFC; o++) acc[o] = bsh[o];
  const float* src = bf + (size_t)b * kC * kHW + p;
#pragma unroll 4
  for (int c = 0; c < kC; c++) {
    float v = src[(size_t)c * kHW];
#pragma unroll
    for (int o = 0; o < kAFC; o++) acc[o] += v * w[o * kC + c];
  }
  float* dst = feats + (size_t)b * kAFC * kHW + p;
#pragma unroll
  for (int o = 0; o < kAFC; o++) dst[(size_t)o * kHW] = acc[o];
}

// ---------------- gather rois -> baf (bf16) ----------------
__global__ __launch_bounds__(256) void k_gather(const float* __restrict__ feats,
                                                const int* __restrict__ cut,
                                                const void* __restrict__ mask,
                                                const int* __restrict__ flag,
                                                short* __restrict__ baf) {
  int idx = blockIdx.x * 256 + threadIdx.x;
  if (idx >= kB * kN * kH) return;
  int b = idx / (kN * kH);
  int r = idx % (kN * kH);
  int n = r / kH, h = r % kH;
  int f = *flag;
  bool inv;
  if (f == 0)      inv = ((const int*)mask)[r] != 0;
  else if (f == 1) inv = ((const unsigned char*)mask)[r] != 0;
  else             inv = ((const float*)mask)[r] != 0.0f;
  int x = cut[r];
  short* dst = baf + (size_t)(b * kN + n) * kD + h;
  if (inv) {
#pragma unroll
    for (int a = 0; a < kAFC; a++) dst[a * kH] = 0;
  } else {
    const float* sp = feats + (size_t)b * kAFC * kHW + (size_t)h * kW + x;
#pragma unroll
    for (int a = 0; a < kAFC; a++) dst[a * kH] = f2bf(sp[(size_t)a * kHW]);
  }
}

// ---------------- transpose baf -> bafT [b][d][n_pad] (zero-pad n>=1000) ----
__global__ __launch_bounds__(256) void k_transpose(const short* __restrict__ baf,
                                                   short* __restrict__ bafT) {
  __shared__ short t[64][66];
  int b = blockIdx.z, n0 = blockIdx.y * 64, d0 = blockIdx.x * 64;
  int c = threadIdx.x & 63, r4 = threadIdx.x >> 6;  // c: 0..63, r4: 0..3
#pragma unroll
  for (int i = 0; i < 16; i++) {
    int nl = r4 + i * 4;
    int n = n0 + nl;
    short v = (n < kN) ? baf[(size_t)(b * kN + n) * kD + d0 + c] : (short)0;
    t[nl][c] = v;
  }
  __syncthreads();
#pragma unroll
  for (int i = 0; i < 16; i++) {
    int dl = r4 + i * 4;
    bafT[((size_t)b * kD + d0 + dl) * kNP + n0 + c] = t[c][dl];
  }
}

// ---------------- convert attn_w -> bf16 [1024][2560] (pad rows) ------------
__global__ __launch_bounds__(256) void k_cvt_attnw(const float* __restrict__ w,
                                                   short* __restrict__ o) {
  int idx = blockIdx.x * 256 + threadIdx.x;
  if (idx >= kNP * kD) return;
  int j = idx / kD;
  o[idx] = (j < kNM1) ? f2bf(w[idx]) : (short)0;
}

// ---------------- build head weight bf16 [384][5120] ------------------------
__global__ __launch_bounds__(256) void k_cvt_whead(const float* __restrict__ reg_w,
                                                   const float* __restrict__ cls_w,
                                                   short* __restrict__ o) {
  int idx = blockIdx.x * 256 + threadIdx.x;
  if (idx >= 384 * kK2) return;
  int j = idx / kK2, k = idx % kK2;
  float v = 0.f;
  if (j < 3 * kS)            v = reg_w[idx];
  else if (j < 3 * kS + kNC) v = cls_w[(size_t)(j - 3 * kS) * kK2 + k];
  o[idx] = f2bf(v);
}

// ---------------- softmax: scores -> attn_mat (f32 out) + attn bf16 padded --
__global__ __launch_bounds__(256) void k_softmax(const float* __restrict__ scores,
                                                 const float* __restrict__ anchors,
                                                 float* __restrict__ attn_out,
                                                 short* __restrict__ attn_bf,
                                                 float* __restrict__ rp) {
  int m = blockIdx.x;           // 0..15999
  int b = m / kN;
  int i = m % kN;
  const float* srow = scores + (size_t)m * kNM1;
  int tid = threadIdx.x;
  __shared__ float red[4];
  float v[4];
  float mx = -INFINITY;
#pragma unroll
  for (int t = 0; t < 4; t++) {
    int j = tid + t * 256;
    v[t] = (j < kNM1) ? srow[j] : -INFINITY;
    mx = fmaxf(mx, v[t]);
  }
#pragma unroll
  for (int o = 32; o; o >>= 1) mx = fmaxf(mx, __shfl_down(mx, o));
  if ((tid & 63) == 0) red[tid >> 6] = mx;
  __syncthreads();
  mx = fmaxf(fmaxf(red[0], red[1]), fmaxf(red[2], red[3]));
  __syncthreads();
  float s = 0.f;
#pragma unroll
  for (int t = 0; t < 4; t++) {
    int j = tid + t * 256;
    v[t] = (j < kNM1) ? __expf(v[t] - mx) : 0.f;
    s += v[t];
  }
#pragma unroll
  for (int o = 32; o; o >>= 1) s += __shfl_down(s, o);
  if ((tid & 63) == 0) red[tid >> 6] = s;
  __syncthreads();
  s = red[0] + red[1] + red[2] + red[3];
  float inv = 1.0f / s;
  float* orow = attn_out + (size_t)m * kN;
  short* brow = attn_bf + ((size_t)b * kNP + i) * kNP;
#pragma unroll
  for (int t = 0; t < 4; t++) {
    int j = tid + t * 256;
    if (j < kNM1) {
      int dst = j + (j >= i);
      float p = v[t] * inv;
      orow[dst] = p;
      brow[dst] = f2bf(p);
    }
  }
  if (tid == 0) { orow[i] = 0.f; brow[i] = 0; }
  if (tid < kNP - kN) brow[kN + tid] = 0;           // pad cols 1000..1023
  if (tid < 3) rp[(size_t)m * kRP + 2 + tid] = anchors[(size_t)i * kRP + 2 + tid];
}

// ---------------- MFMA bf16 GEMM, m97 structure (128x128 tile, BK=32) -------
// 1D grid, decoded so blocks sharing an A-panel are temporally adjacent.
// MODE 0: scores = baf @ attnw^T (+attn_b), f32 out [16000][999]
// MODE 1: attf   = attn @ bafT^T, bf16 out [16][1000][2560], batched
template <int MODE>
__global__ __launch_bounds__(256) void k_mfma_gemm(
    const short* __restrict__ A,
    const short* __restrict__ Bt,
    const float* __restrict__ bias,
    void* __restrict__ Cout, int K, int lda, int ldb) {
  __shared__ short smem[8192];                 // As: 8 KB, Bs: 8 KB
  char* sA = (char*)smem;
  char* sB = (char*)smem + 8192;
  int tid = threadIdx.x, lane = tid & 63, wv = tid >> 6;
  int bid = blockIdx.x;
  int m0, n0, bz = 0;
  const short* Ap = A;
  const short* Bp = Bt;
  if (MODE == 0) {
    // col-tile fastest: 8 col tiles share one A m-panel back-to-back
    m0 = (bid >> 3) * 128; n0 = (bid & 7) * 128;
  } else {
    // per batch: d-tile fastest (20 share one attn m-panel)
    bz = bid / 160;
    int r = bid % 160;
    m0 = (r / 20) * 128; n0 = (r % 20) * 128;
    Ap = A + (size_t)bz * kNP * kNP;
    Bp = Bt + (size_t)bz * kD * kNP;
  }
  int wm = (wv >> 1) * 64, wn = (wv & 1) * 64;
  int sRow = lane >> 2;          // 0..15 row within 16-row chunk
  int sKo  = (lane & 3) * 8;     // k element offset
  f32x4 acc[4][4] = {};

  for (int k0 = 0; k0 < K; k0 += 32) {
    const short* ga = Ap + (size_t)(m0 + 32 * wv + sRow) * lda + k0 + sKo;
    GLOAD_LDS16(ga,            sA + wv * 2048);
    GLOAD_LDS16(ga + 16 * lda, sA + wv * 2048 + 1024);
    const short* gb = Bp + (size_t)(n0 + 32 * wv + sRow) * ldb + k0 + sKo;
    GLOAD_LDS16(gb,            sB + wv * 2048);
    GLOAD_LDS16(gb + 16 * ldb, sB + wv * 2048 + 1024);
    __syncthreads();

    bf16x8 af[4], bfg[4];
#pragma unroll
    for (int i = 0; i < 4; i++)
      af[i] = *(const bf16x8*)(sA + ((size_t)(wm + i * 16 + (lane & 15))) * 64 + (lane >> 4) * 16);
#pragma unroll
    for (int j = 0; j < 4; j++)
      bfg[j] = *(const bf16x8*)(sB + ((size_t)(wn + j * 16 + (lane & 15))) * 64 + (lane >> 4) * 16);
#pragma unroll
    for (int i = 0; i < 4; i++)
#pragma unroll
      for (int j = 0; j < 4; j++)
        acc[i][j] = __builtin_amdgcn_mfma_f32_16x16x32_bf16(af[i], bfg[j], acc[i][j], 0, 0, 0);
    __syncthreads();
  }

  // epilogue
#pragma unroll
  for (int i = 0; i < 4; i++) {
#pragma unroll
    for (int j = 0; j < 4; j++) {
#pragma unroll
      for (int r = 0; r < 4; r++) {
        int row = m0 + wm + i * 16 + (lane >> 4) * 4 + r;
        int col = n0 + wn + j * 16 + (lane & 15);
        float v = acc[i][j][r];
        if (MODE == 0) {
          if (col < kNM1)
            ((float*)Cout)[(size_t)row * kNM1 + col] = v + bias[col];
        } else {
          if (row < kN)
            ((short*)Cout)[((size_t)bz * kN + row) * kD + col] = f2bf(v);
        }
      }
    }
  }
}

// ---------------- head GEMM split-K: BM=64, BN=384, 4 K-chunks --------------
// part[ks][16000][384] = [attf|baf](rows, Kchunk) @ whead^T(:, Kchunk)
__global__ __launch_bounds__(256) void k_head_sk(
    const short* __restrict__ A,   // attf [16000][2560]
    const short* __restrict__ A2,  // baf  [16000][2560]
    const short* __restrict__ Bt,  // whead [384][5120]
    float* __restrict__ part) {
  __shared__ short smem[14336];    // A 4KB + B 24KB, single buffer
  char* sA = (char*)smem;
  char* sB = (char*)smem + 4096;
  int tid = threadIdx.x, lane = tid & 63, wv = tid >> 6;
  int bid = blockIdx.x;
  int ks = bid / (kM / 64);        // K-chunk slow: m-tiles sharing a B-slice adjacent
  int mt = bid % (kM / 64);
  int m0 = mt * 64;
  int kbase = ks * (kK2 / kKS);    // 1280
  int sRow = lane >> 2, sKo = (lane & 3) * 8;
  f32x4 acc[4][6] = {};

  for (int t = 0; t < (kK2 / kKS) / 32; t++) {   // 40 steps
    int k0 = kbase + t * 32;
    const short* Abase = A; int kk = k0;
    if (k0 >= kD) { Abase = A2; kk = k0 - kD; }
    GLOAD_LDS16(Abase + (size_t)(m0 + wv * 16 + sRow) * kD + kk + sKo, sA + wv * 1024);
#pragma unroll
    for (int g = 0; g < 6; g++)
      GLOAD_LDS16(Bt + (size_t)(g * 64 + wv * 16 + sRow) * kK2 + k0 + sKo,
                  sB + g * 4096 + wv * 1024);
    __syncthreads();

    bf16x8 af[4], bfr[6];
#pragma unroll
    for (int i = 0; i < 4; i++)
      af[i] = *(const bf16x8*)(sA + (i * 16 + (lane & 15)) * 64 + (lane >> 4) * 16);
#pragma unroll
    for (int j = 0; j < 6; j++)
      bfr[j] = *(const bf16x8*)(sB + (wv * 96 + j * 16 + (lane & 15)) * 64 + (lane >> 4) * 16);
#pragma unroll
    for (int i = 0; i < 4; i++)
#pragma unroll
      for (int j = 0; j < 6; j++)
        acc[i][j] = __builtin_amdgcn_mfma_f32_16x16x32_bf16(af[i], bfr[j], acc[i][j], 0, 0, 0);
    __syncthreads();
  }

  float* pbase = part + (size_t)ks * kM * 384;
#pragma unroll
  for (int i = 0; i < 4; i++) {
#pragma unroll
    for (int j = 0; j < 6; j++) {
#pragma unroll
      for (int r = 0; r < 4; r++) {
        int row = m0 + i * 16 + (lane >> 4) * 4 + r;
        int col = wv * 96 + j * 16 + (lane & 15);
        pbase[(size_t)row * 384 + col] = acc[i][j][r];
      }
    }
  }
}

// ---------------- head reduce: sum 4 partials + epilogue -> rp --------------
__global__ __launch_bounds__(256) void k_head_reduce(
    const float* __restrict__ part,
    const float* __restrict__ reg_b, const float* __restrict__ cls_b,
    const float* __restrict__ anchors, float* __restrict__ rp) {
  int idx = blockIdx.x * 256 + threadIdx.x;
  if (idx >= kM * 384) return;
  int row = idx / 384, col = idx % 384;
  size_t stride = (size_t)kM * 384;
  float v = part[idx] + part[stride + idx] + part[2 * stride + idx] + part[3 * stride + idx];
  int n = row % kN;
  if (col < 3 * kS) {
    float tv = v + reg_b[col];
    if (col >= 2 * kS) tv = 1.0f / (1.0f + __expf(-tv));
    rp[(size_t)row * kRP + 5 + col] = anchors[(size_t)n * kRP + 5 + col] + tv;
  } else if (col < 3 * kS + kNC) {
    rp[(size_t)row * kRP + (col - 3 * kS)] = v + cls_b[col - 3 * kS];
  }
}

extern "C" void kernel_launch(void* const* d_in, const int* in_sizes, int n_in,
                              void* d_out, int out_size, void* d_ws, size_t ws_size,
                              hipStream_t stream) {
  const float* bf      = (const float*)d_in[0];
  const float* conv_w  = (const float*)d_in[1];
  const float* conv_b  = (const float*)d_in[2];
  const int*   cut     = (const int*)d_in[3];
  const void*  mask    = d_in[4];
  const float* anchors = (const float*)d_in[5];
  const float* attn_w  = (const float*)d_in[6];
  const float* attn_b  = (const float*)d_in[7];
  const float* cls_w   = (const float*)d_in[8];
  const float* cls_b   = (const float*)d_in[9];
  const float* reg_w   = (const float*)d_in[10];
  const float* reg_b   = (const float*)d_in[11];

  float* out    = (float*)d_out;
  float* rp     = out + OFF_RP;
  float* attn_o = out + OFF_ATTN;
  float* feats  = out + OFF_FEAT;

  char*  ws      = (char*)d_ws;
  short* baf     = (short*)(ws + WB_BAF);
  short* bafT    = (short*)(ws + WB_BAFT);
  short* attf    = (short*)(ws + WB_ATTF);
  short* attnw   = (short*)(ws + WB_ATTNW);
  short* whead   = (short*)(ws + WB_WHEAD);
  short* attn_bf = (short*)(ws + WB_ATTNB);
  float* scores  = (float*)(ws + WB_SCORE);
  float* part    = (float*)(ws + WB_PART);
  int*   flag    = (int*)(ws + WB_FLAG);

  k_detect<<<1, 256, 0, stream>>>((const unsigned char*)mask, flag);
  k_conv<<<(kB * kHW) / 256, 256, 0, stream>>>(bf, conv_w, conv_b, feats);
  k_gather<<<(kB * kN * kH) / 256, 256, 0, stream>>>(feats, cut, mask, flag, baf);
  {
    dim3 g(kD / 64, 16, kB);  // d-tiles, n-tiles, batch
    k_transpose<<<g, 256, 0, stream>>>(baf, bafT);
  }
  k_cvt_attnw<<<(kNP * kD + 255) / 256, 256, 0, stream>>>(attn_w, attnw);
  k_cvt_whead<<<(384 * kK2 + 255) / 256, 256, 0, stream>>>(reg_w, cls_w, whead);
  // scores GEMM: 1000 blocks (125 m-tiles x 8 col-tiles, col fastest)
  k_mfma_gemm<0><<<kM / 128 * 8, 256, 0, stream>>>(baf, attnw, attn_b, scores,
                                                   kD, kD, kD);
  k_softmax<<<kM, 256, 0, stream>>>(scores, anchors, attn_o, attn_bf, rp);
  // att GEMM: 2560 blocks (16 b x (8 n-tiles x 20 d-tiles, d fastest))
  k_mfma_gemm<1><<<kB * 8 * 20, 256, 0, stream>>>(attn_bf, bafT, nullptr, attf,
                                                  kNP, kNP, kNP);
  // head GEMM split-K + reduce
  k_head_sk<<<kKS * (kM / 64), 256, 0, stream>>>(attf, baf, whead, part);
  k_head_reduce<<<(kM * 384) / 256, 256, 0, stream>>>(part, reg_b, cls_b,
                                                      anchors, rp);
}